// Round 4
// baseline (205.159 us; speedup 1.0000x reference)
//
#include <hip/hip_runtime.h>
#include <cstdint>
#include <cstddef>

// Problem constants (match reference)
#define BB   64
#define TB   2000
#define KB   256
#define NCHK 500          // TB/4 lse-rows chunks per batch

constexpr float LOG2E = 1.4426950408889634f;
constexpr float LN2f  = 0.6931471805599453f;
constexpr float WBF   = 0.36787944117144233f;   // exp(-1) = blank weight (hat domain)

__device__ __forceinline__ float exp2i(int k) {  // exact 2^k, k in [-126, 127]
  return __uint_as_float((uint32_t)(127 + k) << 23);
}
__device__ __forceinline__ float wmax64(float v) {
#pragma unroll
  for (int m = 32; m >= 1; m >>= 1) v = fmaxf(v, __shfl_xor(v, m, 64));
  return v;
}
__device__ __forceinline__ float wsum64(float v) {
#pragma unroll
  for (int m = 32; m >= 1; m >>= 1) v += __shfl_xor(v, m, 64);
  return v;
}

typedef const __attribute__((address_space(1))) unsigned int* gas1p;
typedef __attribute__((address_space(3))) unsigned int* las3p;

// ---------------------------------------------------------------------------
// Kernel A: blocks [0,64): per-batch linear-domain CTC forward scan.
//   - overlapped (halo) tiling: cross-wave exchange once per 32 steps, 1 barrier
//   - emit rows staged into LDS (double buffer, 32 rows x 1KB each) via
//     global_load_lds width-16: guaranteed full-chunk prefetch lookahead
//   - stale power-of-2 rescale: wave-max reduced in background, applied 8
//     steps later (exact scaling, off the critical path)
// blocks >=64: masked log-sum-exp row partials (4 rows/block).
// ---------------------------------------------------------------------------
__global__ __launch_bounds__(256)
void fsl_main(const float* __restrict__ x, const int* __restrict__ key_lens,
              const int* __restrict__ query_lens, float* __restrict__ partial,
              float* __restrict__ alast, float* __restrict__ aprev) {
  __shared__ __align__(16) char sbuf[65536];   // 2 x 32 rows x 1024B
  __shared__ float4 sP4[2][128];               // halo export, parity-buffered
  __shared__ int    sC[2][4];
  __shared__ float  res2[2];
  __shared__ float  sred[4];

  if (blockIdx.x < BB) {
    __builtin_amdgcn_s_setprio(1);
    const int b    = blockIdx.x;
    const int tid  = threadIdx.x;
    const int lane = tid & 63;
    const int w    = tid >> 6;
    const int p0   = 64 * w - 64 + 2 * lane;
    const int p1   = p0 + 1;
    const int kl   = key_lens[b];
    const int qlen = query_lens[b];
    const float* xb  = x + (size_t)b * (TB * KB);
    const char*  xbc = (const char*)xb;
    const bool isl0  = (lane == 0);
    const int  c0cl  = max(0, min(p0, KB - 2));     // clamped even col
    const int  col4  = c0cl * 4;
    const size_t lane16 = (size_t)lane * 16;

    const float bias0 = (p0 >= 0 && p0 < kl) ? 0.f : -20000.f;
    const float bias1 = (p1 >= 0 && p1 < kl) ? 0.f : -20000.f;

    float a0 = 0.f, b0 = 0.f, a1 = 0.f, b1 = 0.f, s512 = 0.f;
    int Cw = 0;
    float m_red;
    if (p0 == 0) { a0 = WBF; b0 = __builtin_amdgcn_exp2f(LOG2E * xb[0]); }
    {  // initial background max (for the apply at step 8)
      float ml = fmaxf(fmaxf(a0, b0), fmaxf(a1, b1));
      ml = fmaxf(ml, s512);
      m_red = wmax64(ml);
    }

    // stage rows of chunk cc (global rows 1+32*cc .. 32+32*cc, clamped)
#define STAGE(cc) do {                                                       \
    const int tb_ = 1 + 32 * (cc);                                           \
    char* ldsb = sbuf + (((cc) & 1) << 15) + (w << 13);                      \
    const int rr = tb_ + (w << 3);                                           \
    _Pragma("unroll")                                                        \
    for (int j = 0; j < 8; ++j) {                                            \
      const int gr = min(rr + j, TB - 1);                                    \
      __builtin_amdgcn_global_load_lds(                                      \
          (gas1p)(const void*)(xbc + (size_t)gr * 1024 + lane16),            \
          (las3p)(void*)(ldsb + (j << 10)), 16, 0, 0);                       \
    }                                                                        \
  } while (0)

#define STEP(j) do {                                                         \
    const float2 RJ = *(const float2*)(dspc + ((j) << 10));                  \
    float pm1 = __shfl_up(b1, 1, 64);                                        \
    pm1 = isl0 ? 0.0f : pm1;                                                 \
    const float w0k = __builtin_amdgcn_exp2f(fmaf(RJ.x, LOG2E, bias0));      \
    const float w1k = __builtin_amdgcn_exp2f(fmaf(RJ.y, LOG2E, bias1));      \
    const float t0 = a0 + pm1;                                               \
    const float t1 = a1 + b0;                                                \
    const float nb0 = (b0 + t0) * w0k;                                       \
    const float nb1 = (b1 + t1) * w1k;                                       \
    s512 = (s512 + b1) * WBF;                                                \
    a0 = t0 * WBF; a1 = t1 * WBF; b0 = nb0; b1 = nb1;                        \
  } while (0)

#define STEPG(j) do {                                                        \
    const float2 RJ = *(const float2*)(dspc + ((j) << 10));                  \
    float pm1 = __shfl_up(b1, 1, 64);                                        \
    pm1 = isl0 ? 0.0f : pm1;                                                 \
    const float w0k = __builtin_amdgcn_exp2f(fmaf(RJ.x, LOG2E, bias0));      \
    const float w1k = __builtin_amdgcn_exp2f(fmaf(RJ.y, LOG2E, bias1));      \
    const float t0 = a0 + pm1;                                               \
    const float t1 = a1 + b0;                                                \
    const float nb0 = (b0 + t0) * w0k;                                       \
    const float nb1 = (b1 + t1) * w1k;                                       \
    const float ns  = (s512 + b1) * WBF;                                     \
    const bool lv = (j) < rem;                                               \
    a0 = lv ? t0 * WBF : a0; a1 = lv ? t1 * WBF : a1;                        \
    b0 = lv ? nb0 : b0;      b1 = lv ? nb1 : b1;                             \
    s512 = lv ? ns : s512;                                                   \
  } while (0)

    // apply the (stale) power-of-2 rescale; exact, off critical path
#define APPLY() do {                                                         \
    int e = (int)((__float_as_uint(m_red) >> 23) & 0xFF) - 127;              \
    e = (m_red > 0.f) ? e : 0;                                               \
    const float sc = exp2i(-e);                                              \
    a0 *= sc; b0 *= sc; a1 *= sc; b1 *= sc; s512 *= sc; Cw += e;             \
  } while (0)
    // launch background wave-max reduction (consumed 8 steps later)
#define MEASURE() do {                                                       \
    float ml = fmaxf(fmaxf(a0, b0), fmaxf(a1, b1));                          \
    ml = fmaxf(ml, s512);                                                    \
    m_red = wmax64(ml);                                                      \
  } while (0)

    // halo re-import + scale unification: ONE barrier per 32 steps
#define SYNC(cc) do {                                                        \
    APPLY();                                                                 \
    if (lane >= 32) sP4[(cc) & 1][32 * w - 32 + lane] =                      \
        make_float4(a0, b0, a1, b1);                                         \
    if (lane == 32) sC[(cc) & 1][w] = Cw;                                    \
    __syncthreads();                                                         \
    const int Cl = (w > 0) ? sC[(cc) & 1][w - 1] : Cw;                       \
    const int d = Cl - Cw;                                                   \
    if (d > 0) {            /* adopt larger left scale: never overflow */    \
      const int dcn = min(d, 252), dh = dcn >> 1;                            \
      const float s1 = exp2i(-dh), s2 = exp2i(-(dcn - dh));                  \
      a0 = a0*s1*s2; b0 = b0*s1*s2; a1 = a1*s1*s2; b1 = b1*s1*s2;            \
      s512 = s512*s1*s2; Cw = Cl;                                            \
    }                                                                        \
    if (w > 0 && lane < 32) {                                                \
      const float4 v = sP4[(cc) & 1][32 * w - 32 + lane];                    \
      const int dc = max(min(d, 0), -252); const int dh2 = dc >> 1;          \
      const float f1 = exp2i(dh2), f2 = exp2i(dc - dh2);                     \
      a0 = v.x*f1*f2; b0 = v.y*f1*f2; a1 = v.z*f1*f2; b1 = v.w*f1*f2;        \
    }                                                                        \
    MEASURE();                                                               \
  } while (0)

#define S8(S, B) do { S(B); S(B+1); S(B+2); S(B+3); S(B+4); S(B+5); S(B+6); S(B+7); } while (0)

    const int TOT = qlen - 1;         // live steps t = 1 .. qlen-1
    const int NF  = TOT >> 5;
    const int rem = TOT & 31;
    const int NCH = NF + (rem ? 1 : 0);

    STAGE(0);
    __syncthreads();                  // drains stage(0), publishes buf0

    for (int c = 0; c < NF; ++c) {
      if (c + 1 < NCH) STAGE(c + 1);
      const char* dspc = sbuf + ((c & 1) << 15) + col4;
      S8(STEP, 0);  APPLY(); MEASURE();
      S8(STEP, 8);  APPLY(); MEASURE();
      S8(STEP, 16); APPLY(); MEASURE();
      S8(STEP, 24);
      SYNC(c);
    }
    if (rem) {                        // guarded tail chunk (no stage, no sync)
      const char* dspc = sbuf + ((NF & 1) << 15) + col4;
      S8(STEPG, 0);  APPLY(); MEASURE();
      S8(STEPG, 8);  APPLY(); MEASURE();
      S8(STEPG, 16); APPLY(); MEASURE();
      S8(STEPG, 24);
    }
#undef STAGE
#undef STEP
#undef STEPG
#undef APPLY
#undef MEASURE
#undef SYNC
#undef S8

    // readout: a_last = state 2*kl, a_prev = state 2*kl-1 (owned lanes only)
    const float fC = (float)Cw;
    if (lane >= 32) {
      if (p0 == kl)     res2[0] = log2f(a0) + fC;
      if (p1 == kl)     res2[0] = log2f(a1) + fC;
      if (p0 == kl - 1) res2[1] = log2f(b0) + fC;
      if (p1 == kl - 1) res2[1] = log2f(b1) + fC;
    }
    if (w == 3 && lane == 63 && kl == 256) {
      res2[0] = log2f(s512) + fC;
      res2[1] = log2f(b1) + fC;       // pair 255 odd = state 511
    }
    __syncthreads();
    if (tid == 0) { alast[b] = res2[0] * LN2f; aprev[b] = res2[1] * LN2f; }

  } else {
    // ---------------- lse row partials ----------------
    const int idx2  = blockIdx.x - BB;          // [0, BB*NCHK)
    const int b     = idx2 / NCHK;
    const int chunk = idx2 - b * NCHK;
    const int wave  = threadIdx.x >> 6;
    const int lane  = threadIdx.x & 63;
    const int t     = chunk * 4 + wave;
    const int kl    = key_lens[b];
    const int qlen  = query_lens[b];

    const float4 v = *(const float4*)(x + ((size_t)b * TB + t) * KB + lane * 4);
    const int c0 = lane * 4;
    float m = -1.0f;                            // blank logit always valid
    if (c0 + 0 < kl) m = fmaxf(m, v.x);
    if (c0 + 1 < kl) m = fmaxf(m, v.y);
    if (c0 + 2 < kl) m = fmaxf(m, v.z);
    if (c0 + 3 < kl) m = fmaxf(m, v.w);
    m = wmax64(m);
    float s = 0.f;
    if (c0 + 0 < kl) s += __builtin_amdgcn_exp2f((v.x - m) * LOG2E);
    if (c0 + 1 < kl) s += __builtin_amdgcn_exp2f((v.y - m) * LOG2E);
    if (c0 + 2 < kl) s += __builtin_amdgcn_exp2f((v.z - m) * LOG2E);
    if (c0 + 3 < kl) s += __builtin_amdgcn_exp2f((v.w - m) * LOG2E);
    s = wsum64(s);
    s += __builtin_amdgcn_exp2f((-1.0f - m) * LOG2E);   // blank term, once
    float lv = fmaf(__builtin_amdgcn_logf(s), LN2f, m);
    if (lane == 0) sred[wave] = (t < qlen) ? lv : 0.f;
    __syncthreads();
    if (threadIdx.x == 0)
      partial[idx2] = (sred[0] + sred[1]) + (sred[2] + sred[3]);
  }
}

// ---------------------------------------------------------------------------
// Kernel B: per-batch SumLse + loss + mean, one block.
// ---------------------------------------------------------------------------
__global__ __launch_bounds__(256)
void fsl_finish(const float* __restrict__ partial, const int* __restrict__ key_lens,
                const float* __restrict__ alast, const float* __restrict__ aprev,
                float* __restrict__ out) {
  const int tid = threadIdx.x;
  const int b = tid >> 2, q = tid & 3;
  float s = 0.f;
  const float* pb = partial + b * NCHK + q * 125;
#pragma unroll 5
  for (int j = 0; j < 125; ++j) s += pb[j];
  s += __shfl_xor(s, 1, 64);
  s += __shfl_xor(s, 2, 64);
  float lossb = 0.f;
  if (q == 0) {
    const float SumLse = s;
    const float al = alast[b], ap = aprev[b];
    const float mx = fmaxf(al, ap);
    const float lae = (mx == -INFINITY) ? -INFINITY
                                        : mx + log1pf(expf(-fabsf(al - ap)));
    const float nll = SumLse - lae;
    const int kl = key_lens[b];
    float lv = nll / (float)max(kl, 1);
    if (nll > 5e29f) lv = 0.f;
    lossb = lv;
  }
  float v = wsum64(lossb);
  __shared__ float sm[4];
  if ((tid & 63) == 0) sm[tid >> 6] = v;
  __syncthreads();
  if (tid == 0) out[0] = ((sm[0] + sm[1]) + (sm[2] + sm[3])) * (1.0f / 64.0f);
}

extern "C" void kernel_launch(void* const* d_in, const int* in_sizes, int n_in,
                              void* d_out, int out_size, void* d_ws, size_t ws_size,
                              hipStream_t stream) {
  const float* x     = (const float*)d_in[0];
  const int*   klens = (const int*)d_in[1];
  const int*   qlens = (const int*)d_in[2];
  float* out = (float*)d_out;

  float* partial = (float*)d_ws;            // BB*NCHK = 32000 floats
  float* alast   = partial + BB * NCHK;     // 64
  float* aprev   = alast + BB;              // 64

  fsl_main  <<<BB + BB * NCHK, 256, 0, stream>>>(x, klens, qlens, partial, alast, aprev);
  fsl_finish<<<1, 256, 0, stream>>>(partial, klens, alast, aprev, out);
}

// Round 5
// 177.087 us; speedup vs baseline: 1.1585x; 1.1585x over previous
//
#include <hip/hip_runtime.h>
#include <cstdint>
#include <cstddef>

// Problem constants (match reference)
#define BB    64
#define TB    2000
#define KB    256
#define WPB   125      // lse waves per batch
#define RPW   16       // rows per lse wave  (125*16 = 2000)
#define NLSEB 2000     // lse blocks (4 waves each) = 64*125/4

constexpr float LOG2E = 1.4426950408889634f;
constexpr float LN2f  = 0.6931471805599453f;
constexpr float WBF   = 0.36787944117144233f;   // exp(-1) = blank weight (hat domain)

__device__ __forceinline__ float exp2i(int k) {  // exact 2^k, k in [-126, 127]
  return __uint_as_float((uint32_t)(127 + k) << 23);
}
__device__ __forceinline__ float wmax64(float v) {
#pragma unroll
  for (int m = 32; m >= 1; m >>= 1) v = fmaxf(v, __shfl_xor(v, m, 64));
  return v;
}
__device__ __forceinline__ float wsum64(float v) {
#pragma unroll
  for (int m = 32; m >= 1; m >>= 1) v += __shfl_xor(v, m, 64);
  return v;
}
// lane i <- lane i-1 (lane 0 <- 0). gfx9 DPP wave_shr:1, VALU-only (no lgkmcnt).
__device__ __forceinline__ float shr1z(float v) {
  return __int_as_float(__builtin_amdgcn_update_dpp(
      0, __float_as_int(v), 0x138, 0xF, 0xF, true));
}

typedef const __attribute__((address_space(1))) unsigned int* gas1p;
typedef __attribute__((address_space(3))) unsigned int* las3p;

// ---------------------------------------------------------------------------
// blocks [0,64): per-batch linear-domain CTC forward scan.
//   - 4 waves, 2 pairs/lane, 64-pair halo; 1 barrier per 32 steps
//   - emit rows double-buffered in LDS via global_load_lds width-16
//   - cross-lane neighbor via DPP wave_shr:1 (keeps lgkmcnt free for ds_read)
//   - stale power-of-2 rescale (exact), applied 8 steps after measurement
//   - LDS padded to ~86KB -> scan blocks own their CU exclusively
// blocks >= 64: masked row log-sum-exp, 16 rows per wave, no max pass.
// ---------------------------------------------------------------------------
__global__ __launch_bounds__(256)
void fsl_main(const float* __restrict__ x, const int* __restrict__ key_lens,
              const int* __restrict__ query_lens, float* __restrict__ partial,
              float* __restrict__ alast, float* __restrict__ aprev) {
  __shared__ __align__(16) char sbuf[81920];   // buf0 @0, buf1 @49152 (32KB used each)
  __shared__ float4 sP4[2][128];               // halo export, parity-buffered
  __shared__ int    sC[2][4];
  __shared__ float  res2[2];

  if (blockIdx.x < BB) {
    const int b    = blockIdx.x;
    const int tid  = threadIdx.x;
    const int lane = tid & 63;
    const int w    = tid >> 6;
    const int p0   = 64 * w - 64 + 2 * lane;
    const int p1   = p0 + 1;
    const int kl   = key_lens[b];
    const int qlen = query_lens[b];
    const float* xb  = x + (size_t)b * (TB * KB);
    const char*  xbc = (const char*)xb;
    const int  c0cl  = max(0, min(p0, KB - 2));     // clamped even col
    const int  col4  = c0cl * 4;
    const size_t lane16 = (size_t)lane * 16;

    const float bias0 = (p0 >= 0 && p0 < kl) ? 0.f : -20000.f;
    const float bias1 = (p1 >= 0 && p1 < kl) ? 0.f : -20000.f;

    float a0 = 0.f, b0 = 0.f, a1 = 0.f, b1 = 0.f, s512 = 0.f;
    int Cw = 0;
    float m_red;
    if (p0 == 0) { a0 = WBF; b0 = __builtin_amdgcn_exp2f(LOG2E * xb[0]); }
    {  // initial background max (consumed at step 8)
      float ml = fmaxf(fmaxf(a0, b0), fmaxf(a1, b1));
      ml = fmaxf(ml, s512);
      m_red = wmax64(ml);
    }

#define STAGE(cc) do {                                                       \
    char* ldsb = sbuf + (((cc) & 1) ? 49152 : 0) + (w << 13);                \
    const int rr = 1 + 32 * (cc) + (w << 3);                                 \
    _Pragma("unroll")                                                        \
    for (int j = 0; j < 8; ++j) {                                            \
      const int gr = min(rr + j, TB - 1);                                    \
      __builtin_amdgcn_global_load_lds(                                      \
          (gas1p)(const void*)(xbc + (size_t)gr * 1024 + lane16),            \
          (las3p)(void*)(ldsb + (j << 10)), 16, 0, 0);                       \
    }                                                                        \
  } while (0)

#define STEP(EJ) do {                                                        \
    const float pm1 = shr1z(b1);                                             \
    const float w0k = __builtin_amdgcn_exp2f(fmaf(EJ.x, LOG2E, bias0));      \
    const float w1k = __builtin_amdgcn_exp2f(fmaf(EJ.y, LOG2E, bias1));      \
    const float t0 = a0 + pm1;                                               \
    const float t1 = a1 + b0;                                                \
    const float nb0 = (b0 + t0) * w0k;                                       \
    const float nb1 = (b1 + t1) * w1k;                                       \
    s512 = (s512 + b1) * WBF;                                                \
    a0 = t0 * WBF; a1 = t1 * WBF; b0 = nb0; b1 = nb1;                        \
  } while (0)

#define STEPG(EJ, TT) do {                                                   \
    const float pm1 = shr1z(b1);                                             \
    const float w0k = __builtin_amdgcn_exp2f(fmaf(EJ.x, LOG2E, bias0));      \
    const float w1k = __builtin_amdgcn_exp2f(fmaf(EJ.y, LOG2E, bias1));      \
    const float t0 = a0 + pm1;                                               \
    const float t1 = a1 + b0;                                                \
    const float nb0 = (b0 + t0) * w0k;                                       \
    const float nb1 = (b1 + t1) * w1k;                                       \
    const float ns  = (s512 + b1) * WBF;                                     \
    const bool lv = (TT) < rem;                                              \
    a0 = lv ? t0 * WBF : a0; a1 = lv ? t1 * WBF : a1;                        \
    b0 = lv ? nb0 : b0;      b1 = lv ? nb1 : b1;                             \
    s512 = lv ? ns : s512;                                                   \
  } while (0)

    // 8 batched ds_read_b64 then 8 steps (no per-step lgkmcnt interference)
#define G8(B) do {                                                           \
    const float2 e0 = *(const float2*)(dspc + (((B) + 0) << 10));            \
    const float2 e1 = *(const float2*)(dspc + (((B) + 1) << 10));            \
    const float2 e2 = *(const float2*)(dspc + (((B) + 2) << 10));            \
    const float2 e3 = *(const float2*)(dspc + (((B) + 3) << 10));            \
    const float2 e4 = *(const float2*)(dspc + (((B) + 4) << 10));            \
    const float2 e5 = *(const float2*)(dspc + (((B) + 5) << 10));            \
    const float2 e6 = *(const float2*)(dspc + (((B) + 6) << 10));            \
    const float2 e7 = *(const float2*)(dspc + (((B) + 7) << 10));            \
    STEP(e0); STEP(e1); STEP(e2); STEP(e3);                                  \
    STEP(e4); STEP(e5); STEP(e6); STEP(e7);                                  \
  } while (0)

#define G8G(B) do {                                                          \
    const float2 e0 = *(const float2*)(dspc + (((B) + 0) << 10));            \
    const float2 e1 = *(const float2*)(dspc + (((B) + 1) << 10));            \
    const float2 e2 = *(const float2*)(dspc + (((B) + 2) << 10));            \
    const float2 e3 = *(const float2*)(dspc + (((B) + 3) << 10));            \
    const float2 e4 = *(const float2*)(dspc + (((B) + 4) << 10));            \
    const float2 e5 = *(const float2*)(dspc + (((B) + 5) << 10));            \
    const float2 e6 = *(const float2*)(dspc + (((B) + 6) << 10));            \
    const float2 e7 = *(const float2*)(dspc + (((B) + 7) << 10));            \
    STEPG(e0,(B)+0); STEPG(e1,(B)+1); STEPG(e2,(B)+2); STEPG(e3,(B)+3);      \
    STEPG(e4,(B)+4); STEPG(e5,(B)+5); STEPG(e6,(B)+6); STEPG(e7,(B)+7);      \
  } while (0)

#define APPLY() do {                                                         \
    int e = (int)((__float_as_uint(m_red) >> 23) & 0xFF) - 127;              \
    e = (m_red > 0.f) ? e : 0;                                               \
    const float sc = exp2i(-e);                                              \
    a0 *= sc; b0 *= sc; a1 *= sc; b1 *= sc; s512 *= sc; Cw += e;             \
  } while (0)
#define MEASURE() do {                                                       \
    float ml = fmaxf(fmaxf(a0, b0), fmaxf(a1, b1));                          \
    ml = fmaxf(ml, s512);                                                    \
    m_red = wmax64(ml);                                                      \
  } while (0)

#define SYNC(cc) do {                                                        \
    APPLY();                                                                 \
    if (lane >= 32) sP4[(cc) & 1][32 * w - 32 + lane] =                      \
        make_float4(a0, b0, a1, b1);                                         \
    if (lane == 32) sC[(cc) & 1][w] = Cw;                                    \
    __syncthreads();                                                         \
    const int Cl = (w > 0) ? sC[(cc) & 1][w - 1] : Cw;                       \
    const int d = Cl - Cw;                                                   \
    if (d > 0) {            /* adopt larger left scale: never overflow */    \
      const int dcn = min(d, 252), dh = dcn >> 1;                            \
      const float s1 = exp2i(-dh), s2 = exp2i(-(dcn - dh));                  \
      a0 = a0*s1*s2; b0 = b0*s1*s2; a1 = a1*s1*s2; b1 = b1*s1*s2;            \
      s512 = s512*s1*s2; Cw = Cl;                                            \
    }                                                                        \
    if (w > 0 && lane < 32) {                                                \
      const float4 v = sP4[(cc) & 1][32 * w - 32 + lane];                    \
      const int dc = max(min(d, 0), -252); const int dh2 = dc >> 1;          \
      const float f1 = exp2i(dh2), f2 = exp2i(dc - dh2);                     \
      a0 = v.x*f1*f2; b0 = v.y*f1*f2; a1 = v.z*f1*f2; b1 = v.w*f1*f2;        \
    }                                                                        \
    MEASURE();                                                               \
  } while (0)

    const int TOT = qlen - 1;         // live steps t = 1 .. qlen-1
    const int NF  = TOT >> 5;
    const int rem = TOT & 31;
    const int NCH = NF + (rem ? 1 : 0);

    STAGE(0);
    __syncthreads();                  // drains stage(0), publishes buf0

    for (int c = 0; c < NF; ++c) {
      if (c + 1 < NCH) STAGE(c + 1);
      const char* dspc = sbuf + ((c & 1) ? 49152 : 0) + col4;
      G8(0);  APPLY(); MEASURE();
      G8(8);  APPLY(); MEASURE();
      G8(16); APPLY(); MEASURE();
      G8(24);
      SYNC(c);
    }
    if (rem) {                        // guarded tail chunk
      const char* dspc = sbuf + ((NF & 1) ? 49152 : 0) + col4;
      G8G(0);  APPLY(); MEASURE();
      G8G(8);  APPLY(); MEASURE();
      G8G(16); APPLY(); MEASURE();
      G8G(24);
    }
#undef STAGE
#undef STEP
#undef STEPG
#undef G8
#undef G8G
#undef APPLY
#undef MEASURE
#undef SYNC

    // readout: a_last = state 2*kl, a_prev = state 2*kl-1 (owned lanes only)
    const float fC = (float)Cw;
    if (lane >= 32) {
      if (p0 == kl)     res2[0] = log2f(a0) + fC;
      if (p1 == kl)     res2[0] = log2f(a1) + fC;
      if (p0 == kl - 1) res2[1] = log2f(b0) + fC;
      if (p1 == kl - 1) res2[1] = log2f(b1) + fC;
    }
    if (w == 3 && lane == 63 && kl == 256) {
      res2[0] = log2f(s512) + fC;
      res2[1] = log2f(b1) + fC;       // pair 255 odd = state 511
    }
    __syncthreads();
    if (tid == 0) { alast[b] = res2[0] * LN2f; aprev[b] = res2[1] * LN2f; }

  } else {
    // ---------------- lse row partials: 16 rows per wave, no max pass ------
    const int gwid = (blockIdx.x - BB) * 4 + (threadIdx.x >> 6);  // [0,8000)
    const int lane = threadIdx.x & 63;
    const int b    = gwid / WPB;
    const int widx = gwid - b * WPB;
    const int kl   = key_lens[b];
    const int qlen = query_lens[b];
    const float* xb = x + (size_t)b * (TB * KB);
    const int c0 = lane * 4;
    const float bA = (c0 + 0 < kl) ? 0.f : -20000.f;
    const float bBv= (c0 + 1 < kl) ? 0.f : -20000.f;
    const float bC = (c0 + 2 < kl) ? 0.f : -20000.f;
    const float bD = (c0 + 3 < kl) ? 0.f : -20000.f;
    float acc = 0.f;
    const int tbase = widx * RPW;
#pragma unroll 4
    for (int k = 0; k < RPW; ++k) {
      const int t = tbase + k;
      const float4 v = *(const float4*)(xb + (size_t)t * KB + c0);
      float s = __builtin_amdgcn_exp2f(fmaf(v.x, LOG2E, bA))
              + __builtin_amdgcn_exp2f(fmaf(v.y, LOG2E, bBv))
              + __builtin_amdgcn_exp2f(fmaf(v.z, LOG2E, bC))
              + __builtin_amdgcn_exp2f(fmaf(v.w, LOG2E, bD));
      s = wsum64(s);
      s += WBF;                                  // blank term exp(-1)
      const float l2 = __builtin_amdgcn_logf(s); // log2(s)
      acc += (t < qlen) ? l2 : 0.f;
    }
    if (lane == 0) partial[gwid] = acc * LN2f;
  }
}

// ---------------------------------------------------------------------------
// finish: per-batch SumLse + loss + mean, one block.
// ---------------------------------------------------------------------------
__global__ __launch_bounds__(256)
void fsl_finish(const float* __restrict__ partial, const int* __restrict__ key_lens,
                const float* __restrict__ alast, const float* __restrict__ aprev,
                float* __restrict__ out) {
  const int tid = threadIdx.x;
  const int b = tid >> 2, q = tid & 3;
  float s = 0.f;
  for (int j = q; j < WPB; j += 4) s += partial[b * WPB + j];
  s += __shfl_xor(s, 1, 64);
  s += __shfl_xor(s, 2, 64);
  float lossb = 0.f;
  if (q == 0) {
    const float SumLse = s;
    const float al = alast[b], ap = aprev[b];
    const float mx = fmaxf(al, ap);
    const float lae = (mx == -INFINITY) ? -INFINITY
                                        : mx + log1pf(expf(-fabsf(al - ap)));
    const float nll = SumLse - lae;
    const int kl = key_lens[b];
    float lv = nll / (float)max(kl, 1);
    if (nll > 5e29f) lv = 0.f;
    lossb = lv;
  }
  float v = wsum64(lossb);
  __shared__ float sm[4];
  if ((tid & 63) == 0) sm[tid >> 6] = v;
  __syncthreads();
  if (tid == 0) out[0] = ((sm[0] + sm[1]) + (sm[2] + sm[3])) * (1.0f / 64.0f);
}

extern "C" void kernel_launch(void* const* d_in, const int* in_sizes, int n_in,
                              void* d_out, int out_size, void* d_ws, size_t ws_size,
                              hipStream_t stream) {
  const float* x     = (const float*)d_in[0];
  const int*   klens = (const int*)d_in[1];
  const int*   qlens = (const int*)d_in[2];
  float* out = (float*)d_out;

  float* partial = (float*)d_ws;            // BB*WPB = 8000 floats
  float* alast   = partial + BB * WPB;      // 64
  float* aprev   = alast + BB;              // 64

  fsl_main  <<<BB + NLSEB, 256, 0, stream>>>(x, klens, qlens, partial, alast, aprev);
  fsl_finish<<<1, 256, 0, stream>>>(partial, klens, alast, aprev, out);
}